// Round 7
// baseline (69.014 us; speedup 1.0000x reference)
//
#include <hip/hip_runtime.h>
#include <hip/hip_bf16.h>
#include <math.h>

// Problem constants
#define DD 64
#define TT 128
#define BBATCH 32
#define BT (BBATCH*TT)         // 4096
#define ND 16                  // Delta truncation: (1-lam)^16 ~ 1.5e-5 for lam=0.5
#define BETA_C 0.8f
#define TWO_PI_R 6.28f         // repo uses 2*3.14
#define LG2_10000 13.28771237954945f

typedef float2 cf;
typedef _Float16 f16;
typedef _Float16 half8 __attribute__((ext_vector_type(8)));
typedef float f32x4 __attribute__((ext_vector_type(4)));

__device__ __forceinline__ void cfma(cf& acc, cf a, cf b){            // acc += a*b
  acc.x = fmaf(a.x, b.x, fmaf(-a.y, b.y, acc.x));
  acc.y = fmaf(a.x, b.y, fmaf( a.y, b.x, acc.y));
}

// ---------------------------------------------------------------------------
// Kernel 1 (front): blocks [0,64) = TC power-chain (register-resident U
// matrices, 4-wave p-split, LDS only for the 64-elem chain vector + partials);
// blocks [64,1088) = prep, 4 bt-rows each (small LDS -> 4 blocks/CU).
// TC blocks first so their serial chain overlaps prep's bulk.
// ---------------------------------------------------------------------------
__global__ __launch_bounds__(256) void k_front(
    const float* __restrict__ mod0, const float* __restrict__ Wp0, const float* __restrict__ bp0,
    const float* __restrict__ mod1, const float* __restrict__ Wp1, const float* __restrict__ bp1,
    const float* __restrict__ mod2, const float* __restrict__ Wp2, const float* __restrict__ bp2,
    const float* __restrict__ smask, const float* __restrict__ ptab,
    const float* __restrict__ Uhr, const float* __restrict__ Uhi,
    const float* __restrict__ Uxr, const float* __restrict__ Uxi,
    const float* __restrict__ Kr,  const float* __restrict__ Ki,
    f16* __restrict__ PsiR, f16* __restrict__ PsiI,
    f16* __restrict__ Cre, f16* __restrict__ Cim, f16* __restrict__ Cmn,
    float* __restrict__ kn)
{
  __shared__ __align__(16) char smem[6560];
  const int tid = threadIdx.x, w = tid >> 6, c = tid & 63;

  if (blockIdx.x < 64) {
    // ---------------- TC: chain t_{D+1} = t_D*Uh, emit C_D = t_D*Ux ------
    cf* st = (cf*)smem;                         // [64]
    cf (*red)[64] = (cf(*)[64])(smem + 512);    // [8][64]
    const int j = blockIdx.x;

    // wave w holds rows p = w*16..w*16+15 of Uh and Ux in registers
    cf uh[16], ux[16];
    #pragma unroll
    for (int i = 0; i < 16; ++i) {
      const int p = w*16 + i;
      uh[i] = make_float2(Uhr[p*64 + c], Uhi[p*64 + c]);
      ux[i] = make_float2(Uxr[p*64 + c], Uxi[p*64 + c]);
    }
    if (w == 0) {
      const cf kj = make_float2(Kr[j*64 + c], -Ki[j*64 + c]);
      st[c] = kj;
      float q = fmaf(kj.x, kj.x, kj.y*kj.y);
      #pragma unroll
      for (int off = 32; off; off >>= 1) q += __shfl_xor(q, off);
      if (c == 0) kn[j] = q;
    }
    __syncthreads();

    for (int D = 0; D < ND; ++D) {
      cf cA = {0.f,0.f}, cB = {0.f,0.f}, tA = {0.f,0.f}, tB = {0.f,0.f};
      #pragma unroll
      for (int i = 0; i < 16; i += 2) {
        const cf t0 = st[w*16 + i], t1 = st[w*16 + i + 1];
        cfma(cA, t0, ux[i]); cfma(cB, t1, ux[i+1]);
        cfma(tA, t0, uh[i]); cfma(tB, t1, uh[i+1]);
      }
      red[w][c]     = make_float2(cA.x + cB.x, cA.y + cB.y);
      red[4 + w][c] = make_float2(tA.x + tB.x, tA.y + tB.y);
      __syncthreads();
      if (w == 0) {
        const cf r0 = red[0][c], r1 = red[1][c], r2 = red[2][c], r3 = red[3][c];
        const float crx = r0.x + r1.x + r2.x + r3.x;
        const float cry = r0.y + r1.y + r2.y + r3.y;
        const size_t row = (size_t)(D*64 + j)*64 + c;
        Cre[row] = (f16)crx;
        Cim[row] = (f16)cry;
        Cmn[row] = (f16)(-cry);
      } else if (w == 1) {
        const cf r0 = red[4][c], r1 = red[5][c], r2 = red[6][c], r3 = red[7][c];
        st[c] = make_float2(r0.x + r1.x + r2.x + r3.x, r0.y + r1.y + r2.y + r3.y);
      }
      __syncthreads();
    }
    return;
  }

  // ---------------- prep: 4 bt rows, wave w owns row w ----------------
  float* s0 = (float*)smem;          // [4][300]
  float* s1 = s0 + 4*300;            // [4][74]
  float* s2 = s1 + 4*74;             // [4][35]
  const int bt0 = (blockIdx.x - 64) * 4;
  {
    const float* g0 = mod0 + (size_t)bt0*300;
    for (int i = tid; i < 4*300; i += 256) s0[i] = g0[i];
    const float* g1 = mod1 + (size_t)bt0*74;
    for (int i = tid; i < 4*74; i += 256) s1[i] = g1[i];
    const float* g2 = mod2 + (size_t)bt0*35;
    for (int i = tid; i < 4*35; i += 256) s2[i] = g2[i];
  }
  __syncthreads();

  float a0 = bp0[c], a1 = bp1[c], a2 = bp2[c];
  const float* r0p = s0 + w*300;
  const float* r1p = s1 + w*74;
  const float* r2p = s2 + w*35;
  for (int p = 0; p < 300; ++p) a0 = fmaf(r0p[p], Wp0[p*64 + c], a0);
  for (int p = 0; p < 74;  ++p) a1 = fmaf(r1p[p], Wp1[p*64 + c], a1);
  for (int p = 0; p < 35;  ++p) a2 = fmaf(r2p[p], Wp2[p*64 + c], a2);

  const int bt = bt0 + w;
  const int t  = bt & (TT-1);
  const float v0 = fmaxf(a0, 0.f), v1 = fmaxf(a1, 0.f), v2 = fmaxf(a2, 0.f);
  float q0 = v0*v0, q1 = v1*v1, q2 = v2*v2;
  #pragma unroll
  for (int off = 32; off; off >>= 1) {
    q0 += __shfl_xor(q0, off);
    q1 += __shfl_xor(q1, off);
    q2 += __shfl_xor(q2, off);
  }
  const float n0 = sqrtf(q0), n1 = sqrtf(q1), n2 = sqrtf(q2);
  const float mx = fmaxf(n0, fmaxf(n1, n2));
  const float e0 = expf(n0 - mx), e1 = expf(n1 - mx), e2 = expf(n2 - mx);
  const float inv = 1.f / (e0 + e1 + e2);
  const float sc0 = sqrtf(e0*inv) / fmaxf(n0, 1e-12f);
  const float sc1 = sqrtf(e1*inv) / fmaxf(n1, 1e-12f);
  const float sc2 = sqrtf(e2*inv) / fmaxf(n2, 1e-12f);

  const int sid = (smask[bt*2 + 1] > smask[bt*2]) ? 1 : 0;
  const float freq = exp2f(-((float)c * (1.f/64.f)) * LG2_10000);
  const float ph = (float)t * freq + ptab[sid*64 + c] * TWO_PI_R;
  float sn, cs;
  sincosf(ph, &sn, &cs);

  const float b0 = v0*sc0, b1v = v1*sc1, b2v = v2*sc2;
  PsiR[(size_t)(0*BT + bt)*64 + c] = (f16)(b0*cs);
  PsiI[(size_t)(0*BT + bt)*64 + c] = (f16)(b0*sn);
  PsiR[(size_t)(1*BT + bt)*64 + c] = (f16)(b1v*cs);
  PsiI[(size_t)(1*BT + bt)*64 + c] = (f16)(b1v*sn);
  PsiR[(size_t)(2*BT + bt)*64 + c] = (f16)(b2v*cs);
  PsiI[(size_t)(2*BT + bt)*64 + c] = (f16)(b2v*sn);
}

// ---------------------------------------------------------------------------
// Kernel 2 (E2): MFMA e-chunks + on-the-fly Delta-convolution + head.
// Grid 256 = (b in [0,32)) x (oct in [0,8)). Block outputs t in
// [oct*16, oct*16+16); psi rows staged for s in [oct*16-16, oct*16+16)
// (2 MFMA col-tiles; tile 0 skipped when oct==0). For each cg==Delta chunk:
// alpha = C_cg * psi_k -> e = sum_k |alpha|^2 scattered as
// p[s+cg][j] += beta*lam*(1-lam)^cg * e  into LDS. Then identity term,
// W1/relu, W2/tanh, log_softmax inline. Eliminates the 16.8 MB e buffer.
// ---------------------------------------------------------------------------
#define PST 76    // psi LDS stride (f16)
#define PBS 67    // p buffer stride (f32)
__global__ __launch_bounds__(256) void k_E2(
    const f16* __restrict__ Cre, const f16* __restrict__ Cim, const f16* __restrict__ Cmn,
    const f16* __restrict__ PsiR, const f16* __restrict__ PsiI,
    const float* __restrict__ kn, const float* __restrict__ Lam,
    const float* __restrict__ W1, const float* __restrict__ b1,
    const float* __restrict__ W2, const float* __restrict__ b2,
    float* __restrict__ out)
{
  __shared__ __align__(16) char smem[29184 + 12864 + 1088 + 128];
  f16 (*sP)[2][32][PST] = (f16(*)[2][32][PST])smem;          // [k][comp][row][m]
  float (*pbuf)[PBS] = (float(*)[PBS])(smem + 29184);        // [48][67]
  float (*h1s)[68] = (float(*)[68])(smem + 29184 + 12864);   // [4][68]
  float (*lg)[8] = (float(*)[8])(smem + 29184 + 12864 + 1088);

  const int b = blockIdx.x >> 3, oct = blockIdx.x & 7;
  const int tid = threadIdx.x, w = tid >> 6, lane = tid & 63;
  const int l15 = lane & 15, l4 = lane >> 4;
  const int sbase = oct*16 - 16;

  for (int i = tid; i < 48*PBS; i += 256) ((float*)pbuf)[i] = 0.f;

  // stage psi: per (k,comp) each thread moves one uint4 (32 rows x 64 f16)
  {
    const int r = tid >> 3, c8 = (tid & 7) << 3;
    int sg = sbase + r; if (sg < 0) sg = 0;    // clamped rows only feed skipped tile
    #pragma unroll
    for (int k = 0; k < 3; ++k) {
      const size_t g = ((size_t)(k*BT + b*TT + sg))*64 + c8;
      *(uint4*)&sP[k][0][r][c8] = *(const uint4*)&PsiR[g];
      *(uint4*)&sP[k][1][r][c8] = *(const uint4*)&PsiI[g];
    }
  }
  __syncthreads();

  const float lam = Lam[0], om = 1.f - lam;
  const int ct0 = (oct == 0) ? 1 : 0;
  float wD = BETA_C * lam;

  for (int cg = 0; cg < 16; ++cg) {
    // A fragments straight from L2 (C chunk rows: wave w owns j in [w16,w16+16))
    const size_t arow = ((size_t)(cg*64 + w*16 + l15))*64 + l4*8;
    half8 aRe[2], aIm[2], aMn[2];
    aRe[0] = *(const half8*)&Cre[arow];      aRe[1] = *(const half8*)&Cre[arow + 32];
    aIm[0] = *(const half8*)&Cim[arow];      aIm[1] = *(const half8*)&Cim[arow + 32];
    aMn[0] = *(const half8*)&Cmn[arow];      aMn[1] = *(const half8*)&Cmn[arow + 32];

    for (int ct = ct0; ct < 2; ++ct) {
      f32x4 eA = {0.f,0.f,0.f,0.f};
      #pragma unroll
      for (int k = 0; k < 3; ++k) {
        f32x4 xr = {0.f,0.f,0.f,0.f}, xi = {0.f,0.f,0.f,0.f};
        #pragma unroll
        for (int kk = 0; kk < 2; ++kk) {
          const half8 bRe = *(const half8*)&sP[k][0][ct*16 + l15][l4*8 + kk*32];
          const half8 bIm = *(const half8*)&sP[k][1][ct*16 + l15][l4*8 + kk*32];
          xr = __builtin_amdgcn_mfma_f32_16x16x32_f16(aRe[kk], bRe, xr, 0, 0, 0);
          xr = __builtin_amdgcn_mfma_f32_16x16x32_f16(aMn[kk], bIm, xr, 0, 0, 0);
          xi = __builtin_amdgcn_mfma_f32_16x16x32_f16(aRe[kk], bIm, xi, 0, 0, 0);
          xi = __builtin_amdgcn_mfma_f32_16x16x32_f16(aIm[kk], bRe, xi, 0, 0, 0);
        }
        #pragma unroll
        for (int r = 0; r < 4; ++r)
          eA[r] = fmaf(xr[r], xr[r], fmaf(xi[r], xi[r], eA[r]));
      }
      // scatter: e[D=cg][j = w16+l4*4+r][s = ct*16+l15] -> p[s_local+cg][j]
      const int pb_ = ct*16 + l15 + cg;
      float* dst = &pbuf[pb_][w*16 + l4*4];
      #pragma unroll
      for (int r = 0; r < 4; ++r) dst[r] += wD * eA[r];
    }
    wD *= om;
  }
  __syncthreads();

  // identity term on the 16 output rows (local rows 16..31)
  for (int i = tid; i < 16*64; i += 256) {
    const int r = i >> 6, jj = i & 63;
    const int t = oct*16 + r;
    const float idt = BETA_C * powf(om, (float)(t + 1)) + (1.f - BETA_C);
    pbuf[16 + r][jj] += idt * kn[jj] * (1.f/64.f);
  }
  // stage W1 into the (now free) psi region
  float* sW1 = (float*)sP;
  for (int i = tid; i < 4096; i += 256) sW1[i] = W1[i];
  __syncthreads();

  // head: 4 groups x 4 rows (wave w -> row g*4+w)
  for (int g = 0; g < 4; ++g) {
    const int r = g*4 + w;
    float acc = b1[lane];
    for (int d = 0; d < 64; ++d)
      acc = fmaf(pbuf[16 + r][d], sW1[d*64 + lane], acc);
    h1s[w][lane] = fmaxf(acc, 0.f);
    __syncthreads();
    if (lane < 6) {
      float a2 = b2[lane];
      for (int cc = 0; cc < 64; ++cc) a2 = fmaf(h1s[w][cc], W2[cc*6 + lane], a2);
      lg[w][lane] = tanhf(a2);
    }
    __syncthreads();
    if (lane < 6) {
      float mxv = -1e30f;
      #pragma unroll
      for (int n = 0; n < 6; ++n) mxv = fmaxf(mxv, lg[w][n]);
      float se = 0.f;
      #pragma unroll
      for (int n = 0; n < 6; ++n) se += expf(lg[w][n] - mxv);
      out[((size_t)(b*TT + oct*16 + r))*6 + lane] = lg[w][lane] - mxv - logf(se);
    }
    __syncthreads();
  }
}

// ---------------------------------------------------------------------------
extern "C" void kernel_launch(void* const* d_in, const int* in_sizes, int n_in,
                              void* d_out, int out_size, void* d_ws, size_t ws_size,
                              hipStream_t stream)
{
  const float* mod0  = (const float*)d_in[0];
  const float* Wp0   = (const float*)d_in[1];
  const float* bp0   = (const float*)d_in[2];
  const float* mod1  = (const float*)d_in[3];
  const float* Wp1   = (const float*)d_in[4];
  const float* bp1   = (const float*)d_in[5];
  const float* mod2  = (const float*)d_in[6];
  const float* Wp2   = (const float*)d_in[7];
  const float* bp2   = (const float*)d_in[8];
  const float* smask = (const float*)d_in[9];
  const float* ptab  = (const float*)d_in[11];
  const float* Uhr   = (const float*)d_in[12];
  const float* Uhi   = (const float*)d_in[13];
  const float* Uxr   = (const float*)d_in[14];
  const float* Uxi   = (const float*)d_in[15];
  const float* Lam   = (const float*)d_in[16];
  const float* Kr    = (const float*)d_in[17];
  const float* Ki    = (const float*)d_in[18];
  const float* W1    = (const float*)d_in[19];
  const float* b1    = (const float*)d_in[20];
  const float* W2    = (const float*)d_in[21];
  const float* b2    = (const float*)d_in[22];

  char* ws = (char*)d_ws;
  float* kn   = (float*)(ws);
  f16*   Cre  = (f16*)  (ws + ((size_t)1024 << 10));  // 128KB each
  f16*   Cim  = (f16*)  (ws + ((size_t)1280 << 10));
  f16*   Cmn  = (f16*)  (ws + ((size_t)1536 << 10));
  f16*   PsiR = (f16*)  (ws + ((size_t)2 << 20));     // 512KB each
  f16*   PsiI = (f16*)  (ws + ((size_t)4 << 20));
  if (ws_size < ((size_t)8 << 20)) return;

  k_front<<<1088, 256, 0, stream>>>(mod0, Wp0, bp0, mod1, Wp1, bp1, mod2, Wp2, bp2,
                                    smask, ptab, Uhr, Uhi, Uxr, Uxi, Kr, Ki,
                                    PsiR, PsiI, Cre, Cim, Cmn, kn);
  k_E2<<<256, 256, 0, stream>>>(Cre, Cim, Cmn, PsiR, PsiI, kn, Lam,
                                W1, b1, W2, b2, (float*)d_out);
}

// Round 9
// 57.969 us; speedup vs baseline: 1.1905x; 1.1905x over previous
//
#include <hip/hip_runtime.h>
#include <hip/hip_bf16.h>
#include <math.h>

// Problem constants
#define DD 64
#define TT 128
#define BBATCH 32
#define BT (BBATCH*TT)         // 4096
#define ND 16                  // Delta truncation: (1-lam)^16 ~ 1.5e-5 for lam=0.5
#define BETA_C 0.8f
#define TWO_PI_R 6.28f         // repo uses 2*3.14
#define LG2_10000 13.28771237954945f

typedef float2 cf;
typedef _Float16 f16;
typedef _Float16 half8 __attribute__((ext_vector_type(8)));
typedef float f32x4 __attribute__((ext_vector_type(4)));

__device__ __forceinline__ void cfma(cf& acc, cf a, cf b){            // acc += a*b
  acc.x = fmaf(a.x, b.x, fmaf(-a.y, b.y, acc.x));
  acc.y = fmaf(a.x, b.y, fmaf( a.y, b.x, acc.y));
}

// ---------------------------------------------------------------------------
// Kernel 1 (front): blocks [0,64) = TC power-chain (register-resident U rows,
// 4-wave p-split, tiny LDS); blocks [64,1088) = prep, 4 bt-rows each.
// ---------------------------------------------------------------------------
__global__ __launch_bounds__(256) void k_front(
    const float* __restrict__ mod0, const float* __restrict__ Wp0, const float* __restrict__ bp0,
    const float* __restrict__ mod1, const float* __restrict__ Wp1, const float* __restrict__ bp1,
    const float* __restrict__ mod2, const float* __restrict__ Wp2, const float* __restrict__ bp2,
    const float* __restrict__ smask, const float* __restrict__ ptab,
    const float* __restrict__ Uhr, const float* __restrict__ Uhi,
    const float* __restrict__ Uxr, const float* __restrict__ Uxi,
    const float* __restrict__ Kr,  const float* __restrict__ Ki,
    f16* __restrict__ PsiR, f16* __restrict__ PsiI,
    f16* __restrict__ Cre, f16* __restrict__ Cim, f16* __restrict__ Cmn,
    float* __restrict__ kn)
{
  __shared__ __align__(16) char smem[6720];
  const int tid = threadIdx.x, w = tid >> 6, c = tid & 63;

  if (blockIdx.x < 64) {
    // ---------------- TC: chain t_{D+1} = t_D*Uh, emit C_D = t_D*Ux ------
    cf* st = (cf*)smem;                         // [64]
    cf (*red)[64] = (cf(*)[64])(smem + 512);    // [8][64]
    const int j = blockIdx.x;

    cf uh[16], ux[16];
    #pragma unroll
    for (int i = 0; i < 16; ++i) {
      const int p = w*16 + i;
      uh[i] = make_float2(Uhr[p*64 + c], Uhi[p*64 + c]);
      ux[i] = make_float2(Uxr[p*64 + c], Uxi[p*64 + c]);
    }
    if (w == 0) {
      const cf kj = make_float2(Kr[j*64 + c], -Ki[j*64 + c]);
      st[c] = kj;
      float q = fmaf(kj.x, kj.x, kj.y*kj.y);
      #pragma unroll
      for (int off = 32; off; off >>= 1) q += __shfl_xor(q, off);
      if (c == 0) kn[j] = q;
    }
    __syncthreads();

    for (int D = 0; D < ND; ++D) {
      cf cA = {0.f,0.f}, cB = {0.f,0.f}, tA = {0.f,0.f}, tB = {0.f,0.f};
      #pragma unroll
      for (int i = 0; i < 16; i += 2) {
        const cf t0 = st[w*16 + i], t1 = st[w*16 + i + 1];
        cfma(cA, t0, ux[i]); cfma(cB, t1, ux[i+1]);
        cfma(tA, t0, uh[i]); cfma(tB, t1, uh[i+1]);
      }
      red[w][c]     = make_float2(cA.x + cB.x, cA.y + cB.y);
      red[4 + w][c] = make_float2(tA.x + tB.x, tA.y + tB.y);
      __syncthreads();
      if (w == 0) {
        const cf r0 = red[0][c], r1 = red[1][c], r2 = red[2][c], r3 = red[3][c];
        const float crx = r0.x + r1.x + r2.x + r3.x;
        const float cry = r0.y + r1.y + r2.y + r3.y;
        const size_t row = (size_t)(D*64 + j)*64 + c;
        Cre[row] = (f16)crx;
        Cim[row] = (f16)cry;
        Cmn[row] = (f16)(-cry);
      } else if (w == 1) {
        const cf r0 = red[4][c], r1 = red[5][c], r2 = red[6][c], r3 = red[7][c];
        st[c] = make_float2(r0.x + r1.x + r2.x + r3.x, r0.y + r1.y + r2.y + r3.y);
      }
      __syncthreads();
    }
    return;
  }

  // ---------------- prep: 4 bt rows, wave w owns row w ----------------
  float* s0 = (float*)smem;              // [4][300]
  float* s1 = (float*)(smem + 4800);     // [4][76]
  float* s2 = (float*)(smem + 6016);     // [4][36]
  const int bt0 = (blockIdx.x - 64) * 4;
  {
    const float* g0 = mod0 + (size_t)bt0*300;
    for (int i = tid; i < 4*300; i += 256) s0[i] = g0[i];
    const float* g1 = mod1 + (size_t)bt0*74;
    for (int i = tid; i < 4*74; i += 256) s1[(i/74)*76 + (i%74)] = g1[i];
    const float* g2 = mod2 + (size_t)bt0*35;
    for (int i = tid; i < 4*35; i += 256) s2[(i/35)*36 + (i%35)] = g2[i];
  }
  __syncthreads();

  float a0 = bp0[c], a1 = bp1[c], a2 = bp2[c];
  const float* r0p = s0 + w*300;
  const float* r1p = s1 + w*76;
  const float* r2p = s2 + w*36;
  for (int p = 0; p < 300; p += 4) {
    const float4 m4 = *(const float4*)&r0p[p];
    a0 = fmaf(m4.x, Wp0[(p+0)*64 + c], a0);
    a0 = fmaf(m4.y, Wp0[(p+1)*64 + c], a0);
    a0 = fmaf(m4.z, Wp0[(p+2)*64 + c], a0);
    a0 = fmaf(m4.w, Wp0[(p+3)*64 + c], a0);
  }
  for (int p = 0; p < 72; p += 4) {
    const float4 m4 = *(const float4*)&r1p[p];
    a1 = fmaf(m4.x, Wp1[(p+0)*64 + c], a1);
    a1 = fmaf(m4.y, Wp1[(p+1)*64 + c], a1);
    a1 = fmaf(m4.z, Wp1[(p+2)*64 + c], a1);
    a1 = fmaf(m4.w, Wp1[(p+3)*64 + c], a1);
  }
  a1 = fmaf(r1p[72], Wp1[72*64 + c], a1);
  a1 = fmaf(r1p[73], Wp1[73*64 + c], a1);
  for (int p = 0; p < 32; p += 4) {
    const float4 m4 = *(const float4*)&r2p[p];
    a2 = fmaf(m4.x, Wp2[(p+0)*64 + c], a2);
    a2 = fmaf(m4.y, Wp2[(p+1)*64 + c], a2);
    a2 = fmaf(m4.z, Wp2[(p+2)*64 + c], a2);
    a2 = fmaf(m4.w, Wp2[(p+3)*64 + c], a2);
  }
  a2 = fmaf(r2p[32], Wp2[32*64 + c], a2);
  a2 = fmaf(r2p[33], Wp2[33*64 + c], a2);
  a2 = fmaf(r2p[34], Wp2[34*64 + c], a2);

  const int bt = bt0 + w;
  const int t  = bt & (TT-1);
  const float v0 = fmaxf(a0, 0.f), v1 = fmaxf(a1, 0.f), v2 = fmaxf(a2, 0.f);
  float q0 = v0*v0, q1 = v1*v1, q2 = v2*v2;
  #pragma unroll
  for (int off = 32; off; off >>= 1) {
    q0 += __shfl_xor(q0, off);
    q1 += __shfl_xor(q1, off);
    q2 += __shfl_xor(q2, off);
  }
  const float n0 = sqrtf(q0), n1 = sqrtf(q1), n2 = sqrtf(q2);
  const float mx = fmaxf(n0, fmaxf(n1, n2));
  const float e0 = expf(n0 - mx), e1 = expf(n1 - mx), e2 = expf(n2 - mx);
  const float inv = 1.f / (e0 + e1 + e2);
  const float sc0 = sqrtf(e0*inv) / fmaxf(n0, 1e-12f);
  const float sc1 = sqrtf(e1*inv) / fmaxf(n1, 1e-12f);
  const float sc2 = sqrtf(e2*inv) / fmaxf(n2, 1e-12f);

  const int sid = (smask[bt*2 + 1] > smask[bt*2]) ? 1 : 0;
  const float freq = exp2f(-((float)c * (1.f/64.f)) * LG2_10000);
  const float ph = (float)t * freq + ptab[sid*64 + c] * TWO_PI_R;
  float sn, cs;
  sincosf(ph, &sn, &cs);

  const float b0 = v0*sc0, b1v = v1*sc1, b2v = v2*sc2;
  PsiR[(size_t)(0*BT + bt)*64 + c] = (f16)(b0*cs);
  PsiI[(size_t)(0*BT + bt)*64 + c] = (f16)(b0*sn);
  PsiR[(size_t)(1*BT + bt)*64 + c] = (f16)(b1v*cs);
  PsiI[(size_t)(1*BT + bt)*64 + c] = (f16)(b1v*sn);
  PsiR[(size_t)(2*BT + bt)*64 + c] = (f16)(b2v*cs);
  PsiI[(size_t)(2*BT + bt)*64 + c] = (f16)(b2v*sn);
}

// ---------------------------------------------------------------------------
// Kernel 2 (MFMA): e[bs][Dj] = sum_k |alpha|^2, alpha = C * psi_k (complex).
// Grid 1024 = 64 bsg x 16 cg; 4 waves, wave w owns j in [w*16,w*16+16).
// psi staged once in padded LDS ([64][72] f16: stride 144B -> 2 lanes/bank,
// conflict-free); A-frags hoisted from global (L2); e written as float4.
// FIX vs R8: staging loop covers all 64 rows (idx < 512), not just 0..31.
// ---------------------------------------------------------------------------
#define PST 72
__global__ __launch_bounds__(256) void k_E(
    const f16* __restrict__ Cre, const f16* __restrict__ Cim, const f16* __restrict__ Cmn,
    const f16* __restrict__ PsiR, const f16* __restrict__ PsiI,
    float* __restrict__ e)
{
  __shared__ __align__(16) f16 sP[3][2][64][PST];   // 55.3 KB
  const int bsg = blockIdx.x >> 4, cg = blockIdx.x & 15;
  const int tid = threadIdx.x, w = tid >> 6, lane = tid & 63;
  const int l15 = lane & 15, l4 = lane >> 4;

  // stage psi: 64 rows x 8 col-chunks = 512 uint4 per (k,comp)
  for (int idx = tid; idx < 512; idx += 256) {
    const int r = idx >> 3, c8 = (idx & 7) << 3;
    #pragma unroll
    for (int k = 0; k < 3; ++k) {
      const size_t g = ((size_t)(k*BT + bsg*64 + r))*64 + c8;
      *(uint4*)&sP[k][0][r][c8] = *(const uint4*)&PsiR[g];
      *(uint4*)&sP[k][1][r][c8] = *(const uint4*)&PsiI[g];
    }
  }

  // A fragments from global (L2), rows j = cg*64 + w*16 + l15
  const size_t arow = ((size_t)(cg*64 + w*16 + l15))*64 + l4*8;
  half8 aRe[2], aIm[2], aMn[2];
  aRe[0] = *(const half8*)&Cre[arow]; aRe[1] = *(const half8*)&Cre[arow + 32];
  aIm[0] = *(const half8*)&Cim[arow]; aIm[1] = *(const half8*)&Cim[arow + 32];
  aMn[0] = *(const half8*)&Cmn[arow]; aMn[1] = *(const half8*)&Cmn[arow + 32];
  __syncthreads();

  #pragma unroll
  for (int ct = 0; ct < 4; ++ct) {
    f32x4 eA = {0.f,0.f,0.f,0.f};
    #pragma unroll
    for (int k = 0; k < 3; ++k) {
      f32x4 xr = {0.f,0.f,0.f,0.f}, xi = {0.f,0.f,0.f,0.f};
      #pragma unroll
      for (int kk = 0; kk < 2; ++kk) {
        const half8 bRe = *(const half8*)&sP[k][0][ct*16 + l15][l4*8 + kk*32];
        const half8 bIm = *(const half8*)&sP[k][1][ct*16 + l15][l4*8 + kk*32];
        xr = __builtin_amdgcn_mfma_f32_16x16x32_f16(aRe[kk], bRe, xr, 0, 0, 0);
        xr = __builtin_amdgcn_mfma_f32_16x16x32_f16(aMn[kk], bIm, xr, 0, 0, 0);
        xi = __builtin_amdgcn_mfma_f32_16x16x32_f16(aRe[kk], bIm, xi, 0, 0, 0);
        xi = __builtin_amdgcn_mfma_f32_16x16x32_f16(aIm[kk], bRe, xi, 0, 0, 0);
      }
      #pragma unroll
      for (int r = 0; r < 4; ++r)
        eA[r] = fmaf(xr[r], xr[r], fmaf(xi[r], xi[r], eA[r]));
    }
    // s = ct*16 + l15 ; j = w*16 + l4*4 + r  (verified C/D layout from R2)
    float4 ev = make_float4(eA[0], eA[1], eA[2], eA[3]);
    *(float4*)&e[(size_t)(bsg*64 + ct*16 + l15)*1024 + cg*64 + w*16 + l4*4] = ev;
  }
}

// ---------------------------------------------------------------------------
// Kernel 3: Delta-convolution + identity term + MLP head + log_softmax.
// p[b,t,j] = beta*lam*sum_D (1-lam)^D e[b,t-D][D*64+j] + (beta*(1-lam)^(t+1)+1-beta)*kn_j/64
// Block = 4 bt x 64 threads.
// ---------------------------------------------------------------------------
__global__ __launch_bounds__(256) void k_head(const float* __restrict__ e,
    const float* __restrict__ kn, const float* __restrict__ Lam,
    const float* __restrict__ W1, const float* __restrict__ b1,
    const float* __restrict__ W2, const float* __restrict__ b2,
    float* __restrict__ out)
{
  __shared__ float pr[4][64];
  __shared__ float h1[4][64];
  __shared__ float lg[4][6];
  const int q = threadIdx.x >> 6, j = threadIdx.x & 63;
  const int bt = blockIdx.x*4 + q;
  const int b = bt >> 7, t = bt & (TT-1);
  const float lam = Lam[0], om = 1.f - lam;

  float acc = 0.f, wD = BETA_C * lam;
  const int nd = min(ND, t + 1);
  for (int D = 0; D < nd; ++D) {
    acc += wD * e[(size_t)(b*TT + t - D)*1024 + D*64 + j];
    wD *= om;
  }
  const float omt = powf(om, (float)(t + 1));
  acc += (BETA_C*omt + (1.f - BETA_C)) * kn[j] * (1.f/64.f);
  pr[q][j] = acc;
  __syncthreads();

  float a1 = b1[j];
  for (int dd = 0; dd < 64; ++dd) a1 = fmaf(pr[q][dd], W1[dd*64 + j], a1);
  h1[q][j] = fmaxf(a1, 0.f);
  __syncthreads();

  if (j < 6) {
    float a2 = b2[j];
    for (int c = 0; c < 64; ++c) a2 = fmaf(h1[q][c], W2[c*6 + j], a2);
    lg[q][j] = tanhf(a2);
  }
  __syncthreads();
  if (j < 6) {
    float mx = -1e30f;
    #pragma unroll
    for (int n = 0; n < 6; ++n) mx = fmaxf(mx, lg[q][n]);
    float se = 0.f;
    #pragma unroll
    for (int n = 0; n < 6; ++n) se += expf(lg[q][n] - mx);
    out[bt*6 + j] = lg[q][j] - mx - logf(se);
  }
}

// ---------------------------------------------------------------------------
extern "C" void kernel_launch(void* const* d_in, const int* in_sizes, int n_in,
                              void* d_out, int out_size, void* d_ws, size_t ws_size,
                              hipStream_t stream)
{
  const float* mod0  = (const float*)d_in[0];
  const float* Wp0   = (const float*)d_in[1];
  const float* bp0   = (const float*)d_in[2];
  const float* mod1  = (const float*)d_in[3];
  const float* Wp1   = (const float*)d_in[4];
  const float* bp1   = (const float*)d_in[5];
  const float* mod2  = (const float*)d_in[6];
  const float* Wp2   = (const float*)d_in[7];
  const float* bp2   = (const float*)d_in[8];
  const float* smask = (const float*)d_in[9];
  const float* ptab  = (const float*)d_in[11];
  const float* Uhr   = (const float*)d_in[12];
  const float* Uhi   = (const float*)d_in[13];
  const float* Uxr   = (const float*)d_in[14];
  const float* Uxi   = (const float*)d_in[15];
  const float* Lam   = (const float*)d_in[16];
  const float* Kr    = (const float*)d_in[17];
  const float* Ki    = (const float*)d_in[18];
  const float* W1    = (const float*)d_in[19];
  const float* b1    = (const float*)d_in[20];
  const float* W2    = (const float*)d_in[21];
  const float* b2    = (const float*)d_in[22];

  char* ws = (char*)d_ws;
  float* kn   = (float*)(ws);
  f16*   Cre  = (f16*)  (ws + ((size_t)1024 << 10));  // 128KB each
  f16*   Cim  = (f16*)  (ws + ((size_t)1280 << 10));
  f16*   Cmn  = (f16*)  (ws + ((size_t)1536 << 10));
  f16*   PsiR = (f16*)  (ws + ((size_t)2 << 20));     // 1.57MB each
  f16*   PsiI = (f16*)  (ws + ((size_t)4 << 20));
  float* e    = (float*)(ws + ((size_t)6 << 20));     // 16.8MB
  if (ws_size < ((size_t)24 << 20)) return;

  k_front<<<1088, 256, 0, stream>>>(mod0, Wp0, bp0, mod1, Wp1, bp1, mod2, Wp2, bp2,
                                    smask, ptab, Uhr, Uhi, Uxr, Uxi, Kr, Ki,
                                    PsiR, PsiI, Cre, Cim, Cmn, kn);
  k_E<<<1024, 256, 0, stream>>>(Cre, Cim, Cmn, PsiR, PsiI, e);
  k_head<<<1024, 256, 0, stream>>>(e, kn, Lam, W1, b1, W2, b2, (float*)d_out);
}

// Round 10
// 46.763 us; speedup vs baseline: 1.4758x; 1.2396x over previous
//
#include <hip/hip_runtime.h>
#include <hip/hip_bf16.h>
#include <math.h>

// Problem constants
#define DD 64
#define TT 128
#define BBATCH 32
#define BT (BBATCH*TT)         // 4096
#define ND 16                  // Delta truncation: (1-lam)^16 ~ 1.5e-5 for lam=0.5
#define BETA_C 0.8f
#define TWO_PI_R 6.28f         // repo uses 2*3.14
#define LG2_10000 13.28771237954945f
#define SW 328                 // f16 LDS row stride for prep staging (656B, 16B-aligned)

typedef float2 cf;
typedef _Float16 f16;
typedef _Float16 half8 __attribute__((ext_vector_type(8)));
typedef _Float16 half4 __attribute__((ext_vector_type(4)));
typedef float f32x4 __attribute__((ext_vector_type(4)));

__device__ __forceinline__ void cfma(cf& acc, cf a, cf b){            // acc += a*b
  acc.x = fmaf(a.x, b.x, fmaf(-a.y, b.y, acc.x));
  acc.y = fmaf(a.x, b.y, fmaf( a.y, b.x, acc.y));
}

// ---------------------------------------------------------------------------
// prep GEMM phase: rep_tile[16 bt][64 d] += mod_k @ Wp_k via MFMA.
// A = Wp^T rows d (staged transposed f16), B = mod rows bt (f16).
// Fragment addressing identical to the k_E pattern verified in R2-R9:
// A: sWpT[row=w*16+l15][k= s*32 + l4*8], B: sMod[row=l15][same k],
// D: col(l15)=B-row(bt), row(l4*4+r)=A-row(d).
// ---------------------------------------------------------------------------
template<int KDIM, int KPAD>
__device__ __forceinline__ f32x4 prep_phase(
    const float* __restrict__ Wp, const float* __restrict__ modg,
    f16* sWpT, f16* sMod, int tid, int w, int l15, int l4)
{
  __syncthreads();   // previous phase's MFMA reads done before restaging
  constexpr int PAD = KPAD - KDIM;
  for (int i = tid; i < 64*PAD; i += 256) {
    const int r = i / PAD, p = KDIM + (i - r*PAD);
    sWpT[r*SW + p] = (f16)0.f;
  }
  for (int i = tid; i < 16*PAD; i += 256) {
    const int r = i / PAD, p = KDIM + (i - r*PAD);
    sMod[r*SW + p] = (f16)0.f;
  }
  // stage Wp transposed: read [p][c4..c4+3] f32, write 4 f16 rows
  for (int i = tid; i < KDIM*16; i += 256) {
    const int p = i >> 4, c4 = (i & 15) << 2;
    const float4 v = *(const float4*)&Wp[p*64 + c4];
    sWpT[(c4+0)*SW + p] = (f16)v.x;
    sWpT[(c4+1)*SW + p] = (f16)v.y;
    sWpT[(c4+2)*SW + p] = (f16)v.z;
    sWpT[(c4+3)*SW + p] = (f16)v.w;
  }
  // stage mod rows (flat 16*KDIM f32, float4-aligned for bt0 multiple of 16)
  for (int i = tid; i < (16*KDIM)/4; i += 256) {
    const float4 v = *(const float4*)&modg[i*4];
    const float vv[4] = {v.x, v.y, v.z, v.w};
    #pragma unroll
    for (int e2 = 0; e2 < 4; ++e2) {
      const int flat = i*4 + e2;
      const int r = flat / KDIM, p = flat - r*KDIM;
      sMod[r*SW + p] = (f16)vv[e2];
    }
  }
  __syncthreads();
  f32x4 acc = {0.f, 0.f, 0.f, 0.f};
  #pragma unroll
  for (int s = 0; s < KPAD/32; ++s) {
    const half8 a = *(const half8*)&sWpT[(w*16 + l15)*SW + s*32 + l4*8];
    const half8 b = *(const half8*)&sMod[l15*SW + s*32 + l4*8];
    acc = __builtin_amdgcn_mfma_f32_16x16x32_f16(a, b, acc, 0, 0, 0);
  }
  return acc;
}

// ---------------------------------------------------------------------------
// Kernel 1 (front): blocks [0,64) = TC power-chain (register U rows, 4-wave
// p-split); blocks [64,320) = prep via MFMA, 16 bt-rows per block.
// ---------------------------------------------------------------------------
__global__ __launch_bounds__(256) void k_front(
    const float* __restrict__ mod0, const float* __restrict__ Wp0, const float* __restrict__ bp0,
    const float* __restrict__ mod1, const float* __restrict__ Wp1, const float* __restrict__ bp1,
    const float* __restrict__ mod2, const float* __restrict__ Wp2, const float* __restrict__ bp2,
    const float* __restrict__ smask, const float* __restrict__ ptab,
    const float* __restrict__ Uhr, const float* __restrict__ Uhi,
    const float* __restrict__ Uxr, const float* __restrict__ Uxi,
    const float* __restrict__ Kr,  const float* __restrict__ Ki,
    f16* __restrict__ PsiR, f16* __restrict__ PsiI,
    f16* __restrict__ Cre, f16* __restrict__ Cim, f16* __restrict__ Cmn,
    float* __restrict__ kn)
{
  __shared__ __align__(16) char smem[65536];
  const int tid = threadIdx.x, w = tid >> 6, lane = tid & 63;
  const int l15 = lane & 15, l4 = lane >> 4;

  if (blockIdx.x < 64) {
    // ---------------- TC: chain t_{D+1} = t_D*Uh, emit C_D = t_D*Ux ------
    cf* st = (cf*)smem;                         // [64]
    cf (*red)[64] = (cf(*)[64])(smem + 512);    // [8][64]
    const int j = blockIdx.x, c = lane;

    cf uh[16], ux[16];
    #pragma unroll
    for (int i = 0; i < 16; ++i) {
      const int p = w*16 + i;
      uh[i] = make_float2(Uhr[p*64 + c], Uhi[p*64 + c]);
      ux[i] = make_float2(Uxr[p*64 + c], Uxi[p*64 + c]);
    }
    if (w == 0) {
      const cf kj = make_float2(Kr[j*64 + c], -Ki[j*64 + c]);
      st[c] = kj;
      float q = fmaf(kj.x, kj.x, kj.y*kj.y);
      #pragma unroll
      for (int off = 32; off; off >>= 1) q += __shfl_xor(q, off);
      if (c == 0) kn[j] = q;
    }
    __syncthreads();

    for (int D = 0; D < ND; ++D) {
      cf cA = {0.f,0.f}, cB = {0.f,0.f}, tA = {0.f,0.f}, tB = {0.f,0.f};
      #pragma unroll
      for (int i = 0; i < 16; i += 2) {
        const cf t0 = st[w*16 + i], t1 = st[w*16 + i + 1];
        cfma(cA, t0, ux[i]); cfma(cB, t1, ux[i+1]);
        cfma(tA, t0, uh[i]); cfma(tB, t1, uh[i+1]);
      }
      red[w][c]     = make_float2(cA.x + cB.x, cA.y + cB.y);
      red[4 + w][c] = make_float2(tA.x + tB.x, tA.y + tB.y);
      __syncthreads();
      if (w == 0) {
        const cf r0 = red[0][c], r1 = red[1][c], r2 = red[2][c], r3 = red[3][c];
        const float crx = r0.x + r1.x + r2.x + r3.x;
        const float cry = r0.y + r1.y + r2.y + r3.y;
        const size_t row = (size_t)(D*64 + j)*64 + c;
        Cre[row] = (f16)crx;
        Cim[row] = (f16)cry;
        Cmn[row] = (f16)(-cry);
      } else if (w == 1) {
        const cf r0 = red[4][c], r1 = red[5][c], r2 = red[6][c], r3 = red[7][c];
        st[c] = make_float2(r0.x + r1.x + r2.x + r3.x, r0.y + r1.y + r2.y + r3.y);
      }
      __syncthreads();
    }
    return;
  }

  // ---------------- prep: 16 bt rows via 3 MFMA GEMM phases ----------------
  f16* sWpT = (f16*)smem;                        // [64][SW]  41,984 B
  f16* sMod = (f16*)(smem + 41984);              // [16][SW]  10,496 B
  float* repS = (float*)(smem + 52480);          // [3][16][68] 13,056 B
  const int bt0 = (int)(blockIdx.x - 64) * 16;

  const f32x4 a0 = prep_phase<300,320>(Wp0, mod0 + (size_t)bt0*300, sWpT, sMod, tid, w, l15, l4);
  #pragma unroll
  for (int r = 0; r < 4; ++r) {
    const int d = w*16 + l4*4 + r;
    repS[(0*16 + l15)*68 + d] = a0[r] + bp0[d];
  }
  const f32x4 a1 = prep_phase<74,96>(Wp1, mod1 + (size_t)bt0*74, sWpT, sMod, tid, w, l15, l4);
  #pragma unroll
  for (int r = 0; r < 4; ++r) {
    const int d = w*16 + l4*4 + r;
    repS[(1*16 + l15)*68 + d] = a1[r] + bp1[d];
  }
  const f32x4 a2 = prep_phase<35,64>(Wp2, mod2 + (size_t)bt0*35, sWpT, sMod, tid, w, l15, l4);
  #pragma unroll
  for (int r = 0; r < 4; ++r) {
    const int d = w*16 + l4*4 + r;
    repS[(2*16 + l15)*68 + d] = a2[r] + bp2[d];
  }
  __syncthreads();

  // epilogue: thread (btl = tid>>4, g = tid&15) owns d = g*4..g*4+3
  const int btl = tid >> 4, g = tid & 15;
  float4 v0 = *(float4*)&repS[(0*16 + btl)*68 + g*4];
  float4 v1 = *(float4*)&repS[(1*16 + btl)*68 + g*4];
  float4 v2 = *(float4*)&repS[(2*16 + btl)*68 + g*4];
  v0.x = fmaxf(v0.x, 0.f); v0.y = fmaxf(v0.y, 0.f); v0.z = fmaxf(v0.z, 0.f); v0.w = fmaxf(v0.w, 0.f);
  v1.x = fmaxf(v1.x, 0.f); v1.y = fmaxf(v1.y, 0.f); v1.z = fmaxf(v1.z, 0.f); v1.w = fmaxf(v1.w, 0.f);
  v2.x = fmaxf(v2.x, 0.f); v2.y = fmaxf(v2.y, 0.f); v2.z = fmaxf(v2.z, 0.f); v2.w = fmaxf(v2.w, 0.f);

  float q0 = v0.x*v0.x + v0.y*v0.y + v0.z*v0.z + v0.w*v0.w;
  float q1 = v1.x*v1.x + v1.y*v1.y + v1.z*v1.z + v1.w*v1.w;
  float q2 = v2.x*v2.x + v2.y*v2.y + v2.z*v2.z + v2.w*v2.w;
  #pragma unroll
  for (int off = 8; off; off >>= 1) {      // reduce over the 16 g-lanes
    q0 += __shfl_xor(q0, off);
    q1 += __shfl_xor(q1, off);
    q2 += __shfl_xor(q2, off);
  }
  const float n0 = sqrtf(q0), n1 = sqrtf(q1), n2 = sqrtf(q2);
  const float mx = fmaxf(n0, fmaxf(n1, n2));
  const float e0 = expf(n0 - mx), e1 = expf(n1 - mx), e2 = expf(n2 - mx);
  const float inv = 1.f / (e0 + e1 + e2);
  const float sc0 = sqrtf(e0*inv) / fmaxf(n0, 1e-12f);
  const float sc1 = sqrtf(e1*inv) / fmaxf(n1, 1e-12f);
  const float sc2 = sqrtf(e2*inv) / fmaxf(n2, 1e-12f);

  const int btg = bt0 + btl;
  const int t = btg & (TT-1);
  const int sid = (smask[btg*2 + 1] > smask[btg*2]) ? 1 : 0;

  float cs[4], sn[4];
  #pragma unroll
  for (int i = 0; i < 4; ++i) {
    const int d = g*4 + i;
    const float freq = exp2f(-((float)d * (1.f/64.f)) * LG2_10000);
    const float ph = (float)t * freq + ptab[sid*64 + d] * TWO_PI_R;
    sincosf(ph, &sn[i], &cs[i]);
  }
  const float am0[4] = {v0.x*sc0, v0.y*sc0, v0.z*sc0, v0.w*sc0};
  const float am1[4] = {v1.x*sc1, v1.y*sc1, v1.z*sc1, v1.w*sc1};
  const float am2[4] = {v2.x*sc2, v2.y*sc2, v2.z*sc2, v2.w*sc2};
  half4 wr, wi;
  #pragma unroll
  for (int i = 0; i < 4; ++i) { wr[i] = (f16)(am0[i]*cs[i]); wi[i] = (f16)(am0[i]*sn[i]); }
  *(half4*)&PsiR[(size_t)(0*BT + btg)*64 + g*4] = wr;
  *(half4*)&PsiI[(size_t)(0*BT + btg)*64 + g*4] = wi;
  #pragma unroll
  for (int i = 0; i < 4; ++i) { wr[i] = (f16)(am1[i]*cs[i]); wi[i] = (f16)(am1[i]*sn[i]); }
  *(half4*)&PsiR[(size_t)(1*BT + btg)*64 + g*4] = wr;
  *(half4*)&PsiI[(size_t)(1*BT + btg)*64 + g*4] = wi;
  #pragma unroll
  for (int i = 0; i < 4; ++i) { wr[i] = (f16)(am2[i]*cs[i]); wi[i] = (f16)(am2[i]*sn[i]); }
  *(half4*)&PsiR[(size_t)(2*BT + btg)*64 + g*4] = wr;
  *(half4*)&PsiI[(size_t)(2*BT + btg)*64 + g*4] = wi;
}

// ---------------------------------------------------------------------------
// Kernel 2 (MFMA): e[bs][Dj] = sum_k |alpha|^2, alpha = C * psi_k (complex).
// Unchanged from R9 (proven).
// ---------------------------------------------------------------------------
#define PST 72
__global__ __launch_bounds__(256) void k_E(
    const f16* __restrict__ Cre, const f16* __restrict__ Cim, const f16* __restrict__ Cmn,
    const f16* __restrict__ PsiR, const f16* __restrict__ PsiI,
    float* __restrict__ e)
{
  __shared__ __align__(16) f16 sP[3][2][64][PST];   // 55.3 KB
  const int bsg = blockIdx.x >> 4, cg = blockIdx.x & 15;
  const int tid = threadIdx.x, w = tid >> 6, lane = tid & 63;
  const int l15 = lane & 15, l4 = lane >> 4;

  for (int idx = tid; idx < 512; idx += 256) {
    const int r = idx >> 3, c8 = (idx & 7) << 3;
    #pragma unroll
    for (int k = 0; k < 3; ++k) {
      const size_t g = ((size_t)(k*BT + bsg*64 + r))*64 + c8;
      *(uint4*)&sP[k][0][r][c8] = *(const uint4*)&PsiR[g];
      *(uint4*)&sP[k][1][r][c8] = *(const uint4*)&PsiI[g];
    }
  }

  const size_t arow = ((size_t)(cg*64 + w*16 + l15))*64 + l4*8;
  half8 aRe[2], aIm[2], aMn[2];
  aRe[0] = *(const half8*)&Cre[arow]; aRe[1] = *(const half8*)&Cre[arow + 32];
  aIm[0] = *(const half8*)&Cim[arow]; aIm[1] = *(const half8*)&Cim[arow + 32];
  aMn[0] = *(const half8*)&Cmn[arow]; aMn[1] = *(const half8*)&Cmn[arow + 32];
  __syncthreads();

  #pragma unroll
  for (int ct = 0; ct < 4; ++ct) {
    f32x4 eA = {0.f,0.f,0.f,0.f};
    #pragma unroll
    for (int k = 0; k < 3; ++k) {
      f32x4 xr = {0.f,0.f,0.f,0.f}, xi = {0.f,0.f,0.f,0.f};
      #pragma unroll
      for (int kk = 0; kk < 2; ++kk) {
        const half8 bRe = *(const half8*)&sP[k][0][ct*16 + l15][l4*8 + kk*32];
        const half8 bIm = *(const half8*)&sP[k][1][ct*16 + l15][l4*8 + kk*32];
        xr = __builtin_amdgcn_mfma_f32_16x16x32_f16(aRe[kk], bRe, xr, 0, 0, 0);
        xr = __builtin_amdgcn_mfma_f32_16x16x32_f16(aMn[kk], bIm, xr, 0, 0, 0);
        xi = __builtin_amdgcn_mfma_f32_16x16x32_f16(aRe[kk], bIm, xi, 0, 0, 0);
        xi = __builtin_amdgcn_mfma_f32_16x16x32_f16(aIm[kk], bRe, xi, 0, 0, 0);
      }
      #pragma unroll
      for (int r = 0; r < 4; ++r)
        eA[r] = fmaf(xr[r], xr[r], fmaf(xi[r], xi[r], eA[r]));
    }
    float4 ev = make_float4(eA[0], eA[1], eA[2], eA[3]);
    *(float4*)&e[(size_t)(bsg*64 + ct*16 + l15)*1024 + cg*64 + w*16 + l4*4] = ev;
  }
}

// ---------------------------------------------------------------------------
// Kernel 3: Delta-convolution + identity term + MLP head + log_softmax.
// Unchanged from R9 (proven).
// ---------------------------------------------------------------------------
__global__ __launch_bounds__(256) void k_head(const float* __restrict__ e,
    const float* __restrict__ kn, const float* __restrict__ Lam,
    const float* __restrict__ W1, const float* __restrict__ b1,
    const float* __restrict__ W2, const float* __restrict__ b2,
    float* __restrict__ out)
{
  __shared__ float pr[4][64];
  __shared__ float h1[4][64];
  __shared__ float lg[4][6];
  const int q = threadIdx.x >> 6, j = threadIdx.x & 63;
  const int bt = blockIdx.x*4 + q;
  const int b = bt >> 7, t = bt & (TT-1);
  const float lam = Lam[0], om = 1.f - lam;

  float acc = 0.f, wD = BETA_C * lam;
  const int nd = min(ND, t + 1);
  for (int D = 0; D < nd; ++D) {
    acc += wD * e[(size_t)(b*TT + t - D)*1024 + D*64 + j];
    wD *= om;
  }
  const float omt = powf(om, (float)(t + 1));
  acc += (BETA_C*omt + (1.f - BETA_C)) * kn[j] * (1.f/64.f);
  pr[q][j] = acc;
  __syncthreads();

  float a1 = b1[j];
  for (int dd = 0; dd < 64; ++dd) a1 = fmaf(pr[q][dd], W1[dd*64 + j], a1);
  h1[q][j] = fmaxf(a1, 0.f);
  __syncthreads();

  if (j < 6) {
    float a2 = b2[j];
    for (int c = 0; c < 64; ++c) a2 = fmaf(h1[q][c], W2[c*6 + j], a2);
    lg[q][j] = tanhf(a2);
  }
  __syncthreads();
  if (j < 6) {
    float mx = -1e30f;
    #pragma unroll
    for (int n = 0; n < 6; ++n) mx = fmaxf(mx, lg[q][n]);
    float se = 0.f;
    #pragma unroll
    for (int n = 0; n < 6; ++n) se += expf(lg[q][n] - mx);
    out[bt*6 + j] = lg[q][j] - mx - logf(se);
  }
}

// ---------------------------------------------------------------------------
extern "C" void kernel_launch(void* const* d_in, const int* in_sizes, int n_in,
                              void* d_out, int out_size, void* d_ws, size_t ws_size,
                              hipStream_t stream)
{
  const float* mod0  = (const float*)d_in[0];
  const float* Wp0   = (const float*)d_in[1];
  const float* bp0   = (const float*)d_in[2];
  const float* mod1  = (const float*)d_in[3];
  const float* Wp1   = (const float*)d_in[4];
  const float* bp1   = (const float*)d_in[5];
  const float* mod2  = (const float*)d_in[6];
  const float* Wp2   = (const float*)d_in[7];
  const float* bp2   = (const float*)d_in[8];
  const float* smask = (const float*)d_in[9];
  const float* ptab  = (const float*)d_in[11];
  const float* Uhr   = (const float*)d_in[12];
  const float* Uhi   = (const float*)d_in[13];
  const float* Uxr   = (const float*)d_in[14];
  const float* Uxi   = (const float*)d_in[15];
  const float* Lam   = (const float*)d_in[16];
  const float* Kr    = (const float*)d_in[17];
  const float* Ki    = (const float*)d_in[18];
  const float* W1    = (const float*)d_in[19];
  const float* b1    = (const float*)d_in[20];
  const float* W2    = (const float*)d_in[21];
  const float* b2    = (const float*)d_in[22];

  char* ws = (char*)d_ws;
  float* kn   = (float*)(ws);
  f16*   Cre  = (f16*)  (ws + ((size_t)1024 << 10));  // 128KB each
  f16*   Cim  = (f16*)  (ws + ((size_t)1280 << 10));
  f16*   Cmn  = (f16*)  (ws + ((size_t)1536 << 10));
  f16*   PsiR = (f16*)  (ws + ((size_t)2 << 20));     // 1.57MB each
  f16*   PsiI = (f16*)  (ws + ((size_t)4 << 20));
  float* e    = (float*)(ws + ((size_t)6 << 20));     // 16.8MB
  if (ws_size < ((size_t)24 << 20)) return;

  k_front<<<320, 256, 0, stream>>>(mod0, Wp0, bp0, mod1, Wp1, bp1, mod2, Wp2, bp2,
                                   smask, ptab, Uhr, Uhi, Uxr, Uxi, Kr, Ki,
                                   PsiR, PsiI, Cre, Cim, Cmn, kn);
  k_E<<<1024, 256, 0, stream>>>(Cre, Cim, Cmn, PsiR, PsiI, e);
  k_head<<<1024, 256, 0, stream>>>(e, kn, Lam, W1, b1, W2, b2, (float*)d_out);
}